// Round 4
// baseline (238.336 us; speedup 1.0000x reference)
//
#include <hip/hip_runtime.h>
#include <hip/hip_bf16.h>

// TokenEmbedding segment-sum, MI355X. Two-phase gather:
//  Phase 1: boundary-scatter the lower-bound table start[b][t] (tok sorted).
//  Phase 2: ONE WAVE PER TOKEN. Lane owns 64 B of the 4 KB H-row (4x float4
//           spaced 64 apart) -> 4 independent loads in flight per row (4x MLP
//           vs round 2's block-per-token single-load scheme). Non-temporal
//           output stores keep the LLC from evicting the input (134+134 MB
//           > 256 MB LLC), so reads stay LLC-served.
// Uses clang ext_vector float4 (HIP_vector_type rejected by
// __builtin_nontemporal_store).
// Empty runs write zeros (handles poisoned d_out, no memset pass).

#define B_DIM 8
#define L_DIM 4096
#define H_DIM 1024
#define LP1   (L_DIM + 1)

typedef float vf4 __attribute__((ext_vector_type(4)));

__global__ __launch_bounds__(256) void build_starts_kernel(
    const int* __restrict__ tok,   // [B, L] sorted per batch
    int* __restrict__ start)       // [B, L+1]
{
    const int gid = blockIdx.x * 256 + threadIdx.x;   // 0 .. B*L-1
    const int b = gid >> 12;
    const int w = gid & (L_DIM - 1);

    const int* __restrict__ row = tok + (size_t)b * L_DIM;
    const int cur  = row[w];
    const int prev = (w > 0) ? row[w - 1] : -1;

    int* __restrict__ srow = start + (size_t)b * LP1;
    for (int t = prev + 1; t <= cur; ++t) srow[t] = w;
    if (w == L_DIM - 1) {
        for (int t = cur + 1; t <= L_DIM; ++t) srow[t] = L_DIM;
    }
}

__global__ __launch_bounds__(256) void token_seg_sum_kernel(
    const float* __restrict__ seq,   // [B, L, H] fp32
    const int* __restrict__ start,   // [B, L+1]
    float* __restrict__ out)         // [B, L, H] fp32
{
    const int lane = threadIdx.x & 63;
    const int wv   = threadIdx.x >> 6;          // 0..3
    const int bt   = blockIdx.x * 4 + wv;       // one wave per (b,t)
    const int b    = bt >> 12;
    const int t    = bt & (L_DIM - 1);

    const int* __restrict__ srow = start + (size_t)b * LP1;
    const int s = srow[t];
    const int e = srow[t + 1];

    // lane covers float4 positions lane, lane+64, lane+128, lane+192 (of 256)
    const vf4* __restrict__ base =
        (const vf4*)(seq + (size_t)b * L_DIM * H_DIM) + lane;

    vf4 a0 = (vf4)0.f, a1 = (vf4)0.f, a2 = (vf4)0.f, a3 = (vf4)0.f;

    for (int w = s; w < e; ++w) {
        const vf4* __restrict__ r = base + (size_t)w * (H_DIM / 4);
        vf4 v0 = r[0];
        vf4 v1 = r[64];
        vf4 v2 = r[128];
        vf4 v3 = r[192];
        a0 += v0;
        a1 += v1;
        a2 += v2;
        a3 += v3;
    }

    vf4* __restrict__ orow = (vf4*)out + (size_t)bt * (H_DIM / 4) + lane;
    __builtin_nontemporal_store(a0, orow);
    __builtin_nontemporal_store(a1, orow + 64);
    __builtin_nontemporal_store(a2, orow + 128);
    __builtin_nontemporal_store(a3, orow + 192);
}

extern "C" void kernel_launch(void* const* d_in, const int* in_sizes, int n_in,
                              void* d_out, int out_size, void* d_ws, size_t ws_size,
                              hipStream_t stream) {
    const float* seq = (const float*)d_in[0];
    const int*   tok = (const int*)d_in[1];
    float*       out = (float*)d_out;
    int*         start = (int*)d_ws;            // B*(L+1) ints = 131 KB

    build_starts_kernel<<<dim3(B_DIM * L_DIM / 256), dim3(256), 0, stream>>>(tok, start);
    token_seg_sum_kernel<<<dim3(B_DIM * L_DIM / 4), dim3(256), 0, stream>>>(seq, start, out);
}